// Round 17
// baseline (96.129 us; speedup 1.0000x reference)
//
#include <hip/hip_runtime.h>

#define TSTEPS 64
#define NI 8192
#define NO 8192
#define DECAY 0.9375f

typedef __attribute__((ext_vector_type(8))) short bf16x8;   // MFMA A/B frag (4 VGPR)
typedef __attribute__((ext_vector_type(4))) float f32x4;    // MFMA C/D frag

// ---------------------------------------------------------------------------
// Kernel 1 (verbatim r15/r16, passing): spikes -> row-major bf16 S[t][k]
// (1 MB) with in-block layout self-detection on the shared first-4KB window.
// ---------------------------------------------------------------------------
__global__ __launch_bounds__(256) void convert_kernel(const void* sp,
                                                      unsigned short* __restrict__ Sbf) {
    __shared__ int any;
    if (threadIdx.x == 0) any = 0;
    __syncthreads();
    int local = 0;
    const unsigned int* win = (const unsigned int*)sp;   // first 4 KB, both layouts
    #pragma unroll
    for (int i = 0; i < 4; ++i) {
        unsigned int v = win[threadIdx.x * 4 + i];
        if (v & 0xFFFFFF00u) local = 1;
    }
    if (local) atomicOr(&any, 1);
    __syncthreads();
    const int f = any;                                   // 1 => uint8 layout

    const int gid = blockIdx.x * 256 + threadIdx.x;      // 0..65535
    const int t   = gid >> 10;
    const int k0  = (gid & 1023) * 8;
    unsigned h[8];
    #pragma unroll
    for (int e = 0; e < 8; ++e) {
        int gi = t * NI + k0 + e;
        bool b;
        if (f) b = ((const unsigned char*)sp)[gi] != 0;
        else   b = ((const int*)sp)[gi] != 0;
        h[e] = b ? 0x3F80u : 0u;                         // bf16(1.0) = 0x3F80
    }
    uint4 v;
    v.x = h[0] | (h[1] << 16);
    v.y = h[2] | (h[3] << 16);
    v.z = h[4] | (h[5] << 16);
    v.w = h[6] | (h[7] << 16);
    *(uint4*)(Sbf + (size_t)t * NI + k0) = v;
}

// ---------------------------------------------------------------------------
// Triple split (UNCHANGED, passing): w = hi + mid + lo, error <= 2^-22 |w|.
// ---------------------------------------------------------------------------
__device__ __forceinline__ void split3(const float4& x, const float4& y,
                                       bf16x8& hi, bf16x8& mid, bf16x8& lo) {
    float v[8] = {x.x, x.y, x.z, x.w, y.x, y.y, y.z, y.w};
    #pragma unroll
    for (int e = 0; e < 8; ++e) {
        unsigned b   = __float_as_uint(v[e]);
        unsigned hb  = b & 0xFFFF0000u;
        float    r1  = v[e] - __uint_as_float(hb);                // exact
        unsigned r1b = __float_as_uint(r1);
        unsigned mb  = r1b & 0xFFFF0000u;
        float    r2  = r1 - __uint_as_float(mb);                  // exact
        unsigned r2b = __float_as_uint(r2);
        unsigned lr  = (r2b + 0x7FFFu + ((r2b >> 16) & 1u)) >> 16; // RNE bf16
        hi[e]  = (short)(b >> 16);
        mid[e] = (short)(mb >> 16);
        lo[e]  = (short)lr;
    }
}

// ---------------------------------------------------------------------------
// Async global->LDS DMA, 16 B/lane, NON-TEMPORAL (aux=2: CPol NT bit).
// W is a pure stream (zero reuse) — keep it out of L1/L2 allocation so the
// TCP miss-tracking path isn't the in-flight bottleneck.
// ---------------------------------------------------------------------------
__device__ __forceinline__ void gload_lds16_nt(const float* g, float* l) {
    __builtin_amdgcn_global_load_lds(
        (const __attribute__((address_space(1))) void*)g,
        (__attribute__((address_space(3))) void*)l, 16, 0, 2 /* NT */);
}

#define MFMA_BF16 __builtin_amdgcn_mfma_f32_16x16x32_bf16
#define WAIT8() do { asm volatile("s_waitcnt vmcnt(8)" ::: "memory"); \
                     __builtin_amdgcn_sched_barrier(0); } while (0)

// ---------------------------------------------------------------------------
// Kernel 2 (r15/r16 structure, 80.3 µs config; ONE change: NT on streaming
// reads). Skinny GEMM with in-block K-split: block = 32 o-rows; wave w takes
// k-slice (kb*4+w)*512. A staged via swizzled NT global_load_lds (wave-
// private, double-buffered, counted vmcnt(8), no loop barriers); B loads
// non-temporal register loads; end: LDS cross-wave reduce -> one pre-reduced
// 8 KB slice per block (partial = 8 MB).
// partial[ob*4+kb][t*32+o5] = sum_{k in 2048-span kb} W[o][k]*S[k][t]
// ---------------------------------------------------------------------------
__global__ __launch_bounds__(256, 4) void gemm_kernel(const float* __restrict__ W,
                                                      const unsigned short* __restrict__ Sbf,
                                                      float* __restrict__ partial) {
    __shared__ __align__(1024) char smem[33280];  // staging 32 KB / red 33.3 KB

    const int tid  = threadIdx.x;
    const int lane = tid & 63;
    const int w    = tid >> 6;
    const int ob   = blockIdx.x >> 2;   // 256 o-blocks of 32 rows
    const int kb   = blockIdx.x & 3;    // 4 k-spans of 2048
    const int r16  = lane & 15;
    const int kg   = lane >> 4;
    const int o0   = ob * 32;
    const int kblk = (kb * 4 + w) * 512;   // wave-private 512-k slice

    char* wlds = smem + w * 8192;       // wave-private 2-stage staging

    const float* gw[2][2];
    #pragma unroll
    for (int m = 0; m < 2; ++m)
        #pragma unroll
        for (int j = 0; j < 2; ++j) {
            int row  = m * 16 + j * 8 + (lane >> 3);
            int usrc = (lane & 7) ^ ((lane >> 3) & 7);
            gw[m][j] = W + (size_t)(o0 + row) * NI + kblk + usrc * 4;
        }

    int offA[2][2];
    #pragma unroll
    for (int m = 0; m < 2; ++m)
        #pragma unroll
        for (int h = 0; h < 2; ++h)
            offA[m][h] = m * 2048 + r16 * 128 + (((kg * 2 + h) ^ (r16 & 7)) * 16);

    const unsigned short* bp[4];
    #pragma unroll
    for (int n = 0; n < 4; ++n)
        bp[n] = Sbf + (size_t)(n * 16 + r16) * NI + kblk + kg * 8;

    f32x4 acc[2][4];
    #pragma unroll
    for (int m = 0; m < 2; ++m)
        #pragma unroll
        for (int n = 0; n < 4; ++n) acc[m][n] = (f32x4)0.f;

    bf16x8 bX[4], bY[4];

    #define ISSUE_A(cc, stage) do {                                          \
        char* _d = wlds + (stage) * 4096;                                    \
        _Pragma("unroll") for (int m = 0; m < 2; ++m)                        \
        _Pragma("unroll") for (int j = 0; j < 2; ++j)                        \
            gload_lds16_nt(gw[m][j] + (cc) * 32,                             \
                           (float*)(_d + m * 2048 + j * 1024));              \
    } while (0)

    #define ISSUE_B(BB, cc) do {                                             \
        _Pragma("unroll") for (int n = 0; n < 4; ++n)                        \
            BB[n] = __builtin_nontemporal_load(                              \
                        (const bf16x8*)(bp[n] + (cc) * 32));                 \
    } while (0)

    #define COMPUTE(stage, BB) do {                                          \
        const char* _s = wlds + (stage) * 4096;                              \
        _Pragma("unroll") for (int m = 0; m < 2; ++m) {                      \
            float4 a0 = *(const float4*)(_s + offA[m][0]);                   \
            float4 a1 = *(const float4*)(_s + offA[m][1]);                   \
            bf16x8 hi, mid, lo;                                              \
            split3(a0, a1, hi, mid, lo);                                     \
            _Pragma("unroll") for (int n = 0; n < 4; ++n) {                  \
                acc[m][n] = MFMA_BF16(hi,  BB[n], acc[m][n], 0, 0, 0);       \
                acc[m][n] = MFMA_BF16(mid, BB[n], acc[m][n], 0, 0, 0);       \
                acc[m][n] = MFMA_BF16(lo,  BB[n], acc[m][n], 0, 0, 0);       \
            }                                                                \
        }                                                                    \
    } while (0)

    ISSUE_A(0, 0); ISSUE_B(bX, 0);
    ISSUE_A(1, 1); ISSUE_B(bY, 1);

    #pragma unroll 1
    for (int c = 0; c < 16; c += 2) {
        WAIT8();                                   // chunk c landed
        COMPUTE(0, bX);
        ISSUE_A((c + 2) & 15, 0); ISSUE_B(bX, (c + 2) & 15);
        WAIT8();                                   // chunk c+1 landed
        COMPUTE(1, bY);
        ISSUE_A((c + 3) & 15, 1); ISSUE_B(bY, (c + 3) & 15);
    }

    __syncthreads();   // drains vmcnt(0) -> staging LDS reusable
    float (*red)[32][65] = (float (*)[32][65])smem;

    #pragma unroll
    for (int m = 0; m < 2; ++m)
        #pragma unroll
        for (int n = 0; n < 4; ++n)
            #pragma unroll
            for (int r = 0; r < 4; ++r)
                red[w][m * 16 + kg * 4 + r][n * 16 + r16] = acc[m][n][r];
    __syncthreads();

    float* slice = partial + (size_t)blockIdx.x * 2048;
    #pragma unroll
    for (int j = 0; j < 8; ++j) {
        int cell = j * 256 + tid;          // t*32 + o5
        int t = cell >> 5, o5 = cell & 31;
        slice[cell] = red[0][o5][t] + red[1][o5][t] + red[2][o5][t] + red[3][o5][t];
    }
}

// ---------------------------------------------------------------------------
// Kernel 3 (verbatim r16, passing): FUSED 4-span reduce + LIF scan.
// out = [spikes(65 x 8192) as f32 0/1, final mempot(8192)]
// ---------------------------------------------------------------------------
__global__ __launch_bounds__(256) void tail_kernel(const float* __restrict__ partial,
                                                   float* __restrict__ out) {
    const int o  = blockIdx.x * 256 + threadIdx.x;
    const float* base = partial + ((size_t)(o >> 5) * 4) * 2048 + (o & 31);
    float m = 0.f;
    out[o] = 0.f;                                // spike row 0 stays zero
    #pragma unroll 4
    for (int t = 0; t < TSTEPS; ++t) {
        float s = base[t * 32] + base[2048 + t * 32]
                + base[4096 + t * 32] + base[6144 + t * 32];
        m += s;
        bool sp = (m >= 1.0f);
        out[(size_t)(t + 1) * NO + o] = sp ? 1.0f : 0.0f;
        m = sp ? (m - 1.0f) : m * DECAY;
    }
    out[(size_t)(TSTEPS + 1) * NO + o] = m;      // final mempot
}

// ---------------------------------------------------------------------------
extern "C" void kernel_launch(void* const* d_in, const int* in_sizes, int n_in,
                              void* d_out, int out_size, void* d_ws, size_t ws_size,
                              hipStream_t stream) {
    const void*  spikes = d_in[0];
    const float* W      = (const float*)d_in[1];
    float*       out    = (float*)d_out;
    char*        ws     = (char*)d_ws;

    // ws layout: [Sbf 1 MB][partial 8 MB] ~= 9 MB
    unsigned short* Sbf     = (unsigned short*)ws;
    float*          partial = (float*)(ws + (size_t)1048576);

    hipLaunchKernelGGL(convert_kernel, dim3(256),      dim3(256), 0, stream,
                       spikes, Sbf);
    hipLaunchKernelGGL(gemm_kernel,    dim3(1024),     dim3(256), 0, stream,
                       W, Sbf, partial);
    hipLaunchKernelGGL(tail_kernel,    dim3(NO / 256), dim3(256), 0, stream,
                       partial, out);
}

// Round 18
// 81.528 us; speedup vs baseline: 1.1791x; 1.1791x over previous
//
#include <hip/hip_runtime.h>

#define TSTEPS 64
#define NI 8192
#define NO 8192
#define DECAY 0.9375f

typedef __attribute__((ext_vector_type(8))) short bf16x8;   // MFMA A/B frag (4 VGPR)
typedef __attribute__((ext_vector_type(4))) float f32x4;    // MFMA C/D frag

// ---------------------------------------------------------------------------
// Kernel 1 (verbatim r15/r16, passing): spikes -> row-major bf16 S[t][k]
// (1 MB) with in-block layout self-detection on the shared first-4KB window.
// ---------------------------------------------------------------------------
__global__ __launch_bounds__(256) void convert_kernel(const void* sp,
                                                      unsigned short* __restrict__ Sbf) {
    __shared__ int any;
    if (threadIdx.x == 0) any = 0;
    __syncthreads();
    int local = 0;
    const unsigned int* win = (const unsigned int*)sp;   // first 4 KB, both layouts
    #pragma unroll
    for (int i = 0; i < 4; ++i) {
        unsigned int v = win[threadIdx.x * 4 + i];
        if (v & 0xFFFFFF00u) local = 1;
    }
    if (local) atomicOr(&any, 1);
    __syncthreads();
    const int f = any;                                   // 1 => uint8 layout

    const int gid = blockIdx.x * 256 + threadIdx.x;      // 0..65535
    const int t   = gid >> 10;
    const int k0  = (gid & 1023) * 8;
    unsigned h[8];
    #pragma unroll
    for (int e = 0; e < 8; ++e) {
        int gi = t * NI + k0 + e;
        bool b;
        if (f) b = ((const unsigned char*)sp)[gi] != 0;
        else   b = ((const int*)sp)[gi] != 0;
        h[e] = b ? 0x3F80u : 0u;                         // bf16(1.0) = 0x3F80
    }
    uint4 v;
    v.x = h[0] | (h[1] << 16);
    v.y = h[2] | (h[3] << 16);
    v.z = h[4] | (h[5] << 16);
    v.w = h[6] | (h[7] << 16);
    *(uint4*)(Sbf + (size_t)t * NI + k0) = v;
}

// ---------------------------------------------------------------------------
// Triple split (UNCHANGED, passing): w = hi + mid + lo, error <= 2^-22 |w|.
// ---------------------------------------------------------------------------
__device__ __forceinline__ void split3(const float4& x, const float4& y,
                                       bf16x8& hi, bf16x8& mid, bf16x8& lo) {
    float v[8] = {x.x, x.y, x.z, x.w, y.x, y.y, y.z, y.w};
    #pragma unroll
    for (int e = 0; e < 8; ++e) {
        unsigned b   = __float_as_uint(v[e]);
        unsigned hb  = b & 0xFFFF0000u;
        float    r1  = v[e] - __uint_as_float(hb);                // exact
        unsigned r1b = __float_as_uint(r1);
        unsigned mb  = r1b & 0xFFFF0000u;
        float    r2  = r1 - __uint_as_float(mb);                  // exact
        unsigned r2b = __float_as_uint(r2);
        unsigned lr  = (r2b + 0x7FFFu + ((r2b >> 16) & 1u)) >> 16; // RNE bf16
        hi[e]  = (short)(b >> 16);
        mid[e] = (short)(mb >> 16);
        lo[e]  = (short)lr;
    }
}

// ---------------------------------------------------------------------------
// Async global->LDS DMA, 16 B/lane (r13-proven; NT reverted — r17 showed
// NT costs 16 µs on this chip).
// ---------------------------------------------------------------------------
__device__ __forceinline__ void gload_lds16(const float* g, float* l) {
    __builtin_amdgcn_global_load_lds(
        (const __attribute__((address_space(1))) void*)g,
        (__attribute__((address_space(3))) void*)l, 16, 0, 0);
}

#define MFMA_BF16 __builtin_amdgcn_mfma_f32_16x16x32_bf16
#define WAIT8() do { asm volatile("s_waitcnt vmcnt(8)" ::: "memory"); \
                     __builtin_amdgcn_sched_barrier(0); } while (0)

// ---------------------------------------------------------------------------
// Kernel 2 (r16 structure, 80.3 µs config; ONE change: bijective XCD-aware
// blockIdx swizzle). Raw dispatch round-robins XCDs, splitting each o-block's
// 4 kb-siblings (which read the SAME 32 W-rows) across 4 XCD L2s. Swizzle:
// XCD x owns swz in [x*128, x*128+128) = 32 consecutive o-blocks = one
// contiguous 32 MB W partition; kb-siblings co-reside -> full 32 KB rows
// stream through one L2 with DRAM page locality (T1, m192).
// partial[ob*4+kb][t*32+o5] = sum_{k in 2048-span kb} W[o][k]*S[k][t]
// ---------------------------------------------------------------------------
__global__ __launch_bounds__(256, 4) void gemm_kernel(const float* __restrict__ W,
                                                      const unsigned short* __restrict__ Sbf,
                                                      float* __restrict__ partial) {
    __shared__ __align__(1024) char smem[33280];  // staging 32 KB / red 33.3 KB

    const int tid  = threadIdx.x;
    const int lane = tid & 63;
    const int w    = tid >> 6;
    // XCD swizzle: dispatch assigns xcd = blockIdx % 8 (round-robin).
    const int swz  = (blockIdx.x & 7) * 128 + (blockIdx.x >> 3);  // bijective, nwg=1024
    const int ob   = swz >> 2;          // 256 o-blocks of 32 rows
    const int kb   = swz & 3;           // 4 k-spans of 2048
    const int r16  = lane & 15;
    const int kg   = lane >> 4;
    const int o0   = ob * 32;
    const int kblk = (kb * 4 + w) * 512;   // wave-private 512-k slice

    char* wlds = smem + w * 8192;       // wave-private 2-stage staging

    const float* gw[2][2];
    #pragma unroll
    for (int m = 0; m < 2; ++m)
        #pragma unroll
        for (int j = 0; j < 2; ++j) {
            int row  = m * 16 + j * 8 + (lane >> 3);
            int usrc = (lane & 7) ^ ((lane >> 3) & 7);
            gw[m][j] = W + (size_t)(o0 + row) * NI + kblk + usrc * 4;
        }

    int offA[2][2];
    #pragma unroll
    for (int m = 0; m < 2; ++m)
        #pragma unroll
        for (int h = 0; h < 2; ++h)
            offA[m][h] = m * 2048 + r16 * 128 + (((kg * 2 + h) ^ (r16 & 7)) * 16);

    const unsigned short* bp[4];
    #pragma unroll
    for (int n = 0; n < 4; ++n)
        bp[n] = Sbf + (size_t)(n * 16 + r16) * NI + kblk + kg * 8;

    f32x4 acc[2][4];
    #pragma unroll
    for (int m = 0; m < 2; ++m)
        #pragma unroll
        for (int n = 0; n < 4; ++n) acc[m][n] = (f32x4)0.f;

    bf16x8 bX[4], bY[4];

    #define ISSUE_A(cc, stage) do {                                          \
        char* _d = wlds + (stage) * 4096;                                    \
        _Pragma("unroll") for (int m = 0; m < 2; ++m)                        \
        _Pragma("unroll") for (int j = 0; j < 2; ++j)                        \
            gload_lds16(gw[m][j] + (cc) * 32,                                \
                        (float*)(_d + m * 2048 + j * 1024));                 \
    } while (0)

    #define ISSUE_B(BB, cc) do {                                             \
        _Pragma("unroll") for (int n = 0; n < 4; ++n)                        \
            BB[n] = *(const bf16x8*)(bp[n] + (cc) * 32);                     \
    } while (0)

    #define COMPUTE(stage, BB) do {                                          \
        const char* _s = wlds + (stage) * 4096;                              \
        _Pragma("unroll") for (int m = 0; m < 2; ++m) {                      \
            float4 a0 = *(const float4*)(_s + offA[m][0]);                   \
            float4 a1 = *(const float4*)(_s + offA[m][1]);                   \
            bf16x8 hi, mid, lo;                                              \
            split3(a0, a1, hi, mid, lo);                                     \
            _Pragma("unroll") for (int n = 0; n < 4; ++n) {                  \
                acc[m][n] = MFMA_BF16(hi,  BB[n], acc[m][n], 0, 0, 0);       \
                acc[m][n] = MFMA_BF16(mid, BB[n], acc[m][n], 0, 0, 0);       \
                acc[m][n] = MFMA_BF16(lo,  BB[n], acc[m][n], 0, 0, 0);       \
            }                                                                \
        }                                                                    \
    } while (0)

    ISSUE_A(0, 0); ISSUE_B(bX, 0);
    ISSUE_A(1, 1); ISSUE_B(bY, 1);

    #pragma unroll 1
    for (int c = 0; c < 16; c += 2) {
        WAIT8();                                   // chunk c landed
        COMPUTE(0, bX);
        ISSUE_A((c + 2) & 15, 0); ISSUE_B(bX, (c + 2) & 15);
        WAIT8();                                   // chunk c+1 landed
        COMPUTE(1, bY);
        ISSUE_A((c + 3) & 15, 1); ISSUE_B(bY, (c + 3) & 15);
    }

    __syncthreads();   // drains vmcnt(0) -> staging LDS reusable
    float (*red)[32][65] = (float (*)[32][65])smem;

    #pragma unroll
    for (int m = 0; m < 2; ++m)
        #pragma unroll
        for (int n = 0; n < 4; ++n)
            #pragma unroll
            for (int r = 0; r < 4; ++r)
                red[w][m * 16 + kg * 4 + r][n * 16 + r16] = acc[m][n][r];
    __syncthreads();

    float* slice = partial + (size_t)swz * 2048;
    #pragma unroll
    for (int j = 0; j < 8; ++j) {
        int cell = j * 256 + tid;          // t*32 + o5
        int t = cell >> 5, o5 = cell & 31;
        slice[cell] = red[0][o5][t] + red[1][o5][t] + red[2][o5][t] + red[3][o5][t];
    }
}

// ---------------------------------------------------------------------------
// Kernel 3 (verbatim r16, passing): FUSED 4-span reduce + LIF scan.
// out = [spikes(65 x 8192) as f32 0/1, final mempot(8192)]
// ---------------------------------------------------------------------------
__global__ __launch_bounds__(256) void tail_kernel(const float* __restrict__ partial,
                                                   float* __restrict__ out) {
    const int o  = blockIdx.x * 256 + threadIdx.x;
    const float* base = partial + ((size_t)(o >> 5) * 4) * 2048 + (o & 31);
    float m = 0.f;
    out[o] = 0.f;                                // spike row 0 stays zero
    #pragma unroll 4
    for (int t = 0; t < TSTEPS; ++t) {
        float s = base[t * 32] + base[2048 + t * 32]
                + base[4096 + t * 32] + base[6144 + t * 32];
        m += s;
        bool sp = (m >= 1.0f);
        out[(size_t)(t + 1) * NO + o] = sp ? 1.0f : 0.0f;
        m = sp ? (m - 1.0f) : m * DECAY;
    }
    out[(size_t)(TSTEPS + 1) * NO + o] = m;      // final mempot
}

// ---------------------------------------------------------------------------
extern "C" void kernel_launch(void* const* d_in, const int* in_sizes, int n_in,
                              void* d_out, int out_size, void* d_ws, size_t ws_size,
                              hipStream_t stream) {
    const void*  spikes = d_in[0];
    const float* W      = (const float*)d_in[1];
    float*       out    = (float*)d_out;
    char*        ws     = (char*)d_ws;

    // ws layout: [Sbf 1 MB][partial 8 MB] ~= 9 MB
    unsigned short* Sbf     = (unsigned short*)ws;
    float*          partial = (float*)(ws + (size_t)1048576);

    hipLaunchKernelGGL(convert_kernel, dim3(256),      dim3(256), 0, stream,
                       spikes, Sbf);
    hipLaunchKernelGGL(gemm_kernel,    dim3(1024),     dim3(256), 0, stream,
                       W, Sbf, partial);
    hipLaunchKernelGGL(tail_kernel,    dim3(NO / 256), dim3(256), 0, stream,
                       partial, out);
}

// Round 21
// 79.160 us; speedup vs baseline: 1.2144x; 1.0299x over previous
//
#include <hip/hip_runtime.h>

#define TSTEPS 64
#define NI 8192
#define NO 8192
#define DECAY 0.9375f

typedef __attribute__((ext_vector_type(8))) short bf16x8;   // MFMA A/B frag (4 VGPR)
typedef __attribute__((ext_vector_type(4))) float f32x4;    // MFMA C/D frag

// ---------------------------------------------------------------------------
// Kernel 1 (verbatim r15/r16, passing): spikes -> row-major bf16 S[t][k]
// (1 MB) with in-block layout self-detection on the shared first-4KB window.
// ---------------------------------------------------------------------------
__global__ __launch_bounds__(256) void convert_kernel(const void* sp,
                                                      unsigned short* __restrict__ Sbf) {
    __shared__ int any;
    if (threadIdx.x == 0) any = 0;
    __syncthreads();
    int local = 0;
    const unsigned int* win = (const unsigned int*)sp;   // first 4 KB, both layouts
    #pragma unroll
    for (int i = 0; i < 4; ++i) {
        unsigned int v = win[threadIdx.x * 4 + i];
        if (v & 0xFFFFFF00u) local = 1;
    }
    if (local) atomicOr(&any, 1);
    __syncthreads();
    const int f = any;                                   // 1 => uint8 layout

    const int gid = blockIdx.x * 256 + threadIdx.x;      // 0..65535
    const int t   = gid >> 10;
    const int k0  = (gid & 1023) * 8;
    unsigned h[8];
    #pragma unroll
    for (int e = 0; e < 8; ++e) {
        int gi = t * NI + k0 + e;
        bool b;
        if (f) b = ((const unsigned char*)sp)[gi] != 0;
        else   b = ((const int*)sp)[gi] != 0;
        h[e] = b ? 0x3F80u : 0u;                         // bf16(1.0) = 0x3F80
    }
    uint4 v;
    v.x = h[0] | (h[1] << 16);
    v.y = h[2] | (h[3] << 16);
    v.z = h[4] | (h[5] << 16);
    v.w = h[6] | (h[7] << 16);
    *(uint4*)(Sbf + (size_t)t * NI + k0) = v;
}

// ---------------------------------------------------------------------------
// Triple split (UNCHANGED, passing): w = hi + mid + lo, error <= 2^-22 |w|.
// ---------------------------------------------------------------------------
__device__ __forceinline__ void split3(const float4& x, const float4& y,
                                       bf16x8& hi, bf16x8& mid, bf16x8& lo) {
    float v[8] = {x.x, x.y, x.z, x.w, y.x, y.y, y.z, y.w};
    #pragma unroll
    for (int e = 0; e < 8; ++e) {
        unsigned b   = __float_as_uint(v[e]);
        unsigned hb  = b & 0xFFFF0000u;
        float    r1  = v[e] - __uint_as_float(hb);                // exact
        unsigned r1b = __float_as_uint(r1);
        unsigned mb  = r1b & 0xFFFF0000u;
        float    r2  = r1 - __uint_as_float(mb);                  // exact
        unsigned r2b = __float_as_uint(r2);
        unsigned lr  = (r2b + 0x7FFFu + ((r2b >> 16) & 1u)) >> 16; // RNE bf16
        hi[e]  = (short)(b >> 16);
        mid[e] = (short)(mb >> 16);
        lo[e]  = (short)lr;
    }
}

// ---------------------------------------------------------------------------
// Async global->LDS DMA, 16 B/lane (r13-proven; NT reverted per r17).
// ---------------------------------------------------------------------------
__device__ __forceinline__ void gload_lds16(const float* g, float* l) {
    __builtin_amdgcn_global_load_lds(
        (const __attribute__((address_space(1))) void*)g,
        (__attribute__((address_space(3))) void*)l, 16, 0, 0);
}

#define MFMA_BF16 __builtin_amdgcn_mfma_f32_16x16x32_bf16
#define WAIT8() do { asm volatile("s_waitcnt vmcnt(8)" ::: "memory"); \
                     __builtin_amdgcn_sched_barrier(0); } while (0)

// ---------------------------------------------------------------------------
// Kernel 2 (verbatim r16, passing, 80.3 µs config): skinny GEMM with
// in-block K-split and WAVE-PRIVATE LDS staging (the robust variant —
// cross-wave-shared staging failed correctness twice, r19/r20).
// Block = 32 o-rows; wave w takes k-slice (kb*4+w)*512. A staged via
// swizzled global_load_lds (double-buffered, counted vmcnt(8), no loop
// barriers); end: LDS cross-wave reduce -> one pre-reduced 8 KB slice.
// partial[ob*4+kb][t*32+o5] = sum_{k in 2048-span kb} W[o][k]*S[k][t]
// ---------------------------------------------------------------------------
__global__ __launch_bounds__(256, 4) void gemm_kernel(const float* __restrict__ W,
                                                      const unsigned short* __restrict__ Sbf,
                                                      float* __restrict__ partial) {
    __shared__ __align__(1024) char smem[33280];  // staging 32 KB / red 33.3 KB

    const int tid  = threadIdx.x;
    const int lane = tid & 63;
    const int w    = tid >> 6;
    const int ob   = blockIdx.x >> 2;   // 256 o-blocks of 32 rows
    const int kb   = blockIdx.x & 3;    // 4 k-spans of 2048
    const int r16  = lane & 15;
    const int kg   = lane >> 4;
    const int o0   = ob * 32;
    const int kblk = (kb * 4 + w) * 512;   // wave-private 512-k slice

    char* wlds = smem + w * 8192;       // wave-private 2-stage staging

    const float* gw[2][2];
    #pragma unroll
    for (int m = 0; m < 2; ++m)
        #pragma unroll
        for (int j = 0; j < 2; ++j) {
            int row  = m * 16 + j * 8 + (lane >> 3);
            int usrc = (lane & 7) ^ ((lane >> 3) & 7);
            gw[m][j] = W + (size_t)(o0 + row) * NI + kblk + usrc * 4;
        }

    int offA[2][2];
    #pragma unroll
    for (int m = 0; m < 2; ++m)
        #pragma unroll
        for (int h = 0; h < 2; ++h)
            offA[m][h] = m * 2048 + r16 * 128 + (((kg * 2 + h) ^ (r16 & 7)) * 16);

    const unsigned short* bp[4];
    #pragma unroll
    for (int n = 0; n < 4; ++n)
        bp[n] = Sbf + (size_t)(n * 16 + r16) * NI + kblk + kg * 8;

    f32x4 acc[2][4];
    #pragma unroll
    for (int m = 0; m < 2; ++m)
        #pragma unroll
        for (int n = 0; n < 4; ++n) acc[m][n] = (f32x4)0.f;

    bf16x8 bX[4], bY[4];

    #define ISSUE_A(cc, stage) do {                                          \
        char* _d = wlds + (stage) * 4096;                                    \
        _Pragma("unroll") for (int m = 0; m < 2; ++m)                        \
        _Pragma("unroll") for (int j = 0; j < 2; ++j)                        \
            gload_lds16(gw[m][j] + (cc) * 32,                                \
                        (float*)(_d + m * 2048 + j * 1024));                 \
    } while (0)

    #define ISSUE_B(BB, cc) do {                                             \
        _Pragma("unroll") for (int n = 0; n < 4; ++n)                        \
            BB[n] = *(const bf16x8*)(bp[n] + (cc) * 32);                     \
    } while (0)

    #define COMPUTE(stage, BB) do {                                          \
        const char* _s = wlds + (stage) * 4096;                              \
        _Pragma("unroll") for (int m = 0; m < 2; ++m) {                      \
            float4 a0 = *(const float4*)(_s + offA[m][0]);                   \
            float4 a1 = *(const float4*)(_s + offA[m][1]);                   \
            bf16x8 hi, mid, lo;                                              \
            split3(a0, a1, hi, mid, lo);                                     \
            _Pragma("unroll") for (int n = 0; n < 4; ++n) {                  \
                acc[m][n] = MFMA_BF16(hi,  BB[n], acc[m][n], 0, 0, 0);       \
                acc[m][n] = MFMA_BF16(mid, BB[n], acc[m][n], 0, 0, 0);       \
                acc[m][n] = MFMA_BF16(lo,  BB[n], acc[m][n], 0, 0, 0);       \
            }                                                                \
        }                                                                    \
    } while (0)

    ISSUE_A(0, 0); ISSUE_B(bX, 0);
    ISSUE_A(1, 1); ISSUE_B(bY, 1);

    #pragma unroll 1
    for (int c = 0; c < 16; c += 2) {
        WAIT8();                                   // chunk c landed
        COMPUTE(0, bX);
        ISSUE_A((c + 2) & 15, 0); ISSUE_B(bX, (c + 2) & 15);
        WAIT8();                                   // chunk c+1 landed
        COMPUTE(1, bY);
        ISSUE_A((c + 3) & 15, 1); ISSUE_B(bY, (c + 3) & 15);
    }

    __syncthreads();   // drains vmcnt(0) -> staging LDS reusable
    float (*red)[32][65] = (float (*)[32][65])smem;

    #pragma unroll
    for (int m = 0; m < 2; ++m)
        #pragma unroll
        for (int n = 0; n < 4; ++n)
            #pragma unroll
            for (int r = 0; r < 4; ++r)
                red[w][m * 16 + kg * 4 + r][n * 16 + r16] = acc[m][n][r];
    __syncthreads();

    float* slice = partial + (size_t)blockIdx.x * 2048;
    #pragma unroll
    for (int j = 0; j < 8; ++j) {
        int cell = j * 256 + tid;          // t*32 + o5
        int t = cell >> 5, o5 = cell & 31;
        slice[cell] = red[0][o5][t] + red[1][o5][t] + red[2][o5][t] + red[3][o5][t];
    }
}

// ---------------------------------------------------------------------------
// Kernel 3: FUSED 4-span reduce + LIF scan (r16 logic; geometry widened to
// 128 blocks x 64 threads — same 8192 threads over 4x the CUs/L2 ports for
// the L2-resident 8 MB partial; r14's slow version of this shape was
// HBM-bound on a 32 MB partial, which no longer exists).
// out = [spikes(65 x 8192) as f32 0/1, final mempot(8192)]
// ---------------------------------------------------------------------------
__global__ __launch_bounds__(64) void tail_kernel(const float* __restrict__ partial,
                                                  float* __restrict__ out) {
    const int o  = blockIdx.x * 64 + threadIdx.x;
    const float* base = partial + ((size_t)(o >> 5) * 4) * 2048 + (o & 31);
    float m = 0.f;
    out[o] = 0.f;                                // spike row 0 stays zero
    #pragma unroll 4
    for (int t = 0; t < TSTEPS; ++t) {
        float s = base[t * 32] + base[2048 + t * 32]
                + base[4096 + t * 32] + base[6144 + t * 32];
        m += s;
        bool sp = (m >= 1.0f);
        out[(size_t)(t + 1) * NO + o] = sp ? 1.0f : 0.0f;
        m = sp ? (m - 1.0f) : m * DECAY;
    }
    out[(size_t)(TSTEPS + 1) * NO + o] = m;      // final mempot
}

// ---------------------------------------------------------------------------
extern "C" void kernel_launch(void* const* d_in, const int* in_sizes, int n_in,
                              void* d_out, int out_size, void* d_ws, size_t ws_size,
                              hipStream_t stream) {
    const void*  spikes = d_in[0];
    const float* W      = (const float*)d_in[1];
    float*       out    = (float*)d_out;
    char*        ws     = (char*)d_ws;

    // ws layout: [Sbf 1 MB][partial 8 MB] ~= 9 MB
    unsigned short* Sbf     = (unsigned short*)ws;
    float*          partial = (float*)(ws + (size_t)1048576);

    hipLaunchKernelGGL(convert_kernel, dim3(256),     dim3(256), 0, stream,
                       spikes, Sbf);
    hipLaunchKernelGGL(gemm_kernel,    dim3(1024),    dim3(256), 0, stream,
                       W, Sbf, partial);
    hipLaunchKernelGGL(tail_kernel,    dim3(NO / 64), dim3(64),  0, stream,
                       partial, out);
}